// Round 1
// baseline (486.970 us; speedup 1.0000x reference)
//
#include <hip/hip_runtime.h>
#include <math.h>

#define NNODES 50000
#define INF    256
#define OUTF   64
#define NEDGES 800000

#define KB  32   // K tile
#define ATS 68   // A_t LDS stride (16B-aligned rows, spreads banks)

// ---------------------------------------------------------------------------
// GEMM + activation epilogue.
// C = feat[50000x256] @ {Wm, Ws}[256x64]; per element:
//   miu = elu(cm); sig = relu(cs); att = exp(-sig);
//   u = miu*att; v = sig*att*att   -> written to workspace.
// Block: 256 threads, tile M=64, N=64 (all cols), K_BLK=32.
// Each thread: 4x4 micro-tile for BOTH matrices (32 accumulators).
// ---------------------------------------------------------------------------
__global__ __launch_bounds__(256, 2) void gemm_act(
    const float* __restrict__ feat,
    const float* __restrict__ Wm,
    const float* __restrict__ Ws,
    float* __restrict__ u,
    float* __restrict__ v,
    int n_nodes)
{
    __shared__ __align__(16) float A_t[KB][ATS];   // transposed A tile [k][m]
    __shared__ __align__(16) float Bm[KB][OUTF];
    __shared__ __align__(16) float Bs[KB][OUTF];

    const int tid = threadIdx.x;
    const int tx  = tid & 15;   // col group: cols tx*4 .. tx*4+3
    const int ty  = tid >> 4;   // row group: rows ty*4 .. ty*4+3
    const int m0  = blockIdx.x * 64;

    float accm[4][4] = {};
    float accs[4][4] = {};

    for (int kb = 0; kb < INF; kb += KB) {
        // ---- A tile: 64 rows x 32 k, loaded as float4, stored transposed ----
        #pragma unroll
        for (int r = 0; r < 2; ++r) {
            int idx = tid + r * 256;     // float4 index, 512 total
            int row = idx >> 3;          // 0..63
            int q   = idx & 7;           // 0..7 (which float4 in the 32-k row)
            int m   = m0 + row;
            float4 val = make_float4(0.f, 0.f, 0.f, 0.f);
            if (m < n_nodes)
                val = *(const float4*)&feat[(size_t)m * INF + kb + q * 4];
            A_t[q * 4 + 0][row] = val.x;
            A_t[q * 4 + 1][row] = val.y;
            A_t[q * 4 + 2][row] = val.z;
            A_t[q * 4 + 3][row] = val.w;
        }
        // ---- B tiles: 32 k x 64 cols each ----
        #pragma unroll
        for (int r = 0; r < 2; ++r) {
            int idx = tid + r * 256;     // float4 index, 512 total
            int k   = idx >> 4;          // 0..31
            int q   = idx & 15;          // 0..15
            *(float4*)&Bm[k][q * 4] = *(const float4*)&Wm[(size_t)(kb + k) * OUTF + q * 4];
            *(float4*)&Bs[k][q * 4] = *(const float4*)&Ws[(size_t)(kb + k) * OUTF + q * 4];
        }
        __syncthreads();

        #pragma unroll
        for (int k = 0; k < KB; ++k) {
            float4 a4  = *(const float4*)&A_t[k][ty * 4];
            float4 bm4 = *(const float4*)&Bm[k][tx * 4];
            float4 bs4 = *(const float4*)&Bs[k][tx * 4];
            float av[4]  = {a4.x, a4.y, a4.z, a4.w};
            float bmv[4] = {bm4.x, bm4.y, bm4.z, bm4.w};
            float bsv[4] = {bs4.x, bs4.y, bs4.z, bs4.w};
            #pragma unroll
            for (int i = 0; i < 4; ++i) {
                #pragma unroll
                for (int j = 0; j < 4; ++j) {
                    accm[i][j] = fmaf(av[i], bmv[j], accm[i][j]);
                    accs[i][j] = fmaf(av[i], bsv[j], accs[i][j]);
                }
            }
        }
        __syncthreads();
    }

    // ---- epilogue: activations + gating, store u, v ----
    #pragma unroll
    for (int i = 0; i < 4; ++i) {
        int m = m0 + ty * 4 + i;
        if (m >= n_nodes) continue;
        float4 uo, vo;
        float* up = (float*)&uo;
        float* vp = (float*)&vo;
        #pragma unroll
        for (int j = 0; j < 4; ++j) {
            float cm  = accm[i][j];
            float miu = cm > 0.f ? cm : expm1f(cm);   // elu, alpha=1
            float cs  = accs[i][j];
            float sig = cs > 0.f ? cs : 0.f;          // relu
            float att = __expf(-sig);                 // exp(-gamma*sigma), gamma=1
            up[j] = miu * att;
            vp[j] = sig * att * att;
        }
        *(float4*)&u[(size_t)m * OUTF + tx * 4] = uo;
        *(float4*)&v[(size_t)m * OUTF + tx * 4] = vo;
    }
}

// ---------------------------------------------------------------------------
// Edge scatter: one wave per edge, lane = feature column.
//   out_miu[dst] += a1[e] * u[src];  out_sig[dst] += a2[e] * v[src]
// ---------------------------------------------------------------------------
__global__ __launch_bounds__(256) void scatter(
    const int* __restrict__ esrc,
    const int* __restrict__ edst,
    const float* __restrict__ a1,
    const float* __restrict__ a2,
    const float* __restrict__ u,
    const float* __restrict__ v,
    float* __restrict__ outm,
    float* __restrict__ outs)
{
    int gw   = (blockIdx.x * 256 + threadIdx.x) >> 6;  // global wave = edge
    int lane = threadIdx.x & 63;
    if (gw >= NEDGES) return;

    int   s  = esrc[gw];
    int   d  = edst[gw];
    float w1 = a1[gw];
    float w2 = a2[gw];

    float uv = u[(size_t)s * OUTF + lane];
    float vv = v[(size_t)s * OUTF + lane];

    unsafeAtomicAdd(&outm[(size_t)d * OUTF + lane], w1 * uv);
    unsafeAtomicAdd(&outs[(size_t)d * OUTF + lane], w2 * vv);
}

extern "C" void kernel_launch(void* const* d_in, const int* in_sizes, int n_in,
                              void* d_out, int out_size, void* d_ws, size_t ws_size,
                              hipStream_t stream)
{
    const float* feat = (const float*)d_in[0];
    const int*   esrc = (const int*)d_in[1];
    const int*   edst = (const int*)d_in[2];
    const float* a1   = (const float*)d_in[3];
    const float* a2   = (const float*)d_in[4];
    const float* Wm   = (const float*)d_in[5];
    const float* Ws   = (const float*)d_in[6];

    float* outm = (float*)d_out;                       // [N,64] miu_out
    float* outs = outm + (size_t)NNODES * OUTF;        // [N,64] sigma_out
    float* u    = (float*)d_ws;                        // [N,64]
    float* v    = u + (size_t)NNODES * OUTF;           // [N,64]

    // d_out is re-poisoned to 0xAA before every timed launch -> zero it.
    hipMemsetAsync(d_out, 0, (size_t)out_size * sizeof(float), stream);

    gemm_act<<<dim3((NNODES + 63) / 64), dim3(256), 0, stream>>>(
        feat, Wm, Ws, u, v, NNODES);

    scatter<<<dim3((NEDGES + 3) / 4), dim3(256), 0, stream>>>(
        esrc, edst, a1, a2, u, v, outm, outs);
}